// Round 11
// baseline (596.303 us; speedup 1.0000x reference)
//
#include <hip/hip_runtime.h>
#include <hip/hip_bf16.h>
#include <math.h>

#define N_NODES 8192
#define FEAT 512
#define NEGV -9e15f
#define VHPT_W 8704

typedef __attribute__((ext_vector_type(8))) short short8;
typedef __attribute__((ext_vector_type(4))) float floatx4;

// ---- workspace layout (bytes) ----
#define OFF_KH    0UL          // f32 kh [8192][512]
#define OFF_VH    16777216UL   // f32 vh [8192][512]
#define OFF_KHP   33554432UL   // bf16 [8320][512]
#define OFF_VHPT  42074112UL   // bf16 [512][8704]  (padded-position columns)
#define OFF_MASK  50987008UL   // u64 [8192][128]; head reused early for cw (f64[1024])
#define OFF_S     59375616UL   // bf16 S, cap 25165824 elems; head reused early for Ahi/Alo/W*T
#define OFF_PERM  109707264UL
#define OFF_FLAGS 109740032UL
#define OFF_BUCK  109772800UL
#define OFF_META  109805568UL  // ints: [0..4]=boff [5..8]=padded [9..13]=soff(+tot) [14..18]=poff
#define OFF_CMEAN 109806592UL
#define OFF_LINV  109808640UL  // f32 [8192] reciprocal row sums
#define WS_NEEDED 109841408UL
#define CAP_S     25165824L

// aliased (early-lifetime) buffers inside the S region:
#define OFF_AHI   (OFF_S)                 // bf16 [8192][512]
#define OFF_ALO   (OFF_S + 8388608UL)
#define OFF_WKHI  (OFF_S + 16777216UL)    // bf16 [512][512] transposed
#define OFF_WKLO  (OFF_S + 17301504UL)
#define OFF_WVHI  (OFF_S + 17825792UL)
#define OFF_WVLO  (OFF_S + 18350080UL)
#define OFF_CW    (OFF_MASK)              // f64 [512][2] (dead before maskpack)

static __device__ __forceinline__ unsigned short f2bf_bits(float x) {
  __hip_bfloat16 h = __float2bfloat16(x);
  unsigned short u;
  __builtin_memcpy(&u, &h, 2);
  return u;
}
static __device__ __forceinline__ float bf_bits2f(unsigned short u) {
  __hip_bfloat16 h;
  __builtin_memcpy(&h, &u, 2);
  return __bfloat162float(h);
}

// Async 16B/lane global->LDS copy (global_load_lds_dwordx4). LDS side must be
// wave-uniform base + lane*16 — all call sites below satisfy this.
static __device__ __forceinline__ void async_copy16(const void* gptr,
                                                    void* lptr) {
  __builtin_amdgcn_global_load_lds(
      (const __attribute__((address_space(1))) unsigned int*)gptr,
      (__attribute__((address_space(3))) unsigned int*)lptr, 16, 0, 0);
}

// ---------------------------------------------------------------------------
// input f32 -> bf16 hi/lo split (hi = bf16(x), lo = bf16(x - hi))
// ---------------------------------------------------------------------------
__global__ __launch_bounds__(256) void convert_input(
    const float* __restrict__ A, __hip_bfloat16* __restrict__ Ahi,
    __hip_bfloat16* __restrict__ Alo) {
  const long idx = ((long)blockIdx.x * 256 + threadIdx.x) * 4;
  const float4 v = *(const float4*)&A[idx];
  const float vv[4] = {v.x, v.y, v.z, v.w};
  ushort4 hi, lo;
  unsigned short* hp = (unsigned short*)&hi;
  unsigned short* lp = (unsigned short*)&lo;
#pragma unroll
  for (int e = 0; e < 4; e++) {
    unsigned short h = f2bf_bits(vv[e]);
    hp[e] = h;
    lp[e] = f2bf_bits(vv[e] - bf_bits2f(h));
  }
  *(ushort4*)&Ahi[idx] = hi;
  *(ushort4*)&Alo[idx] = lo;
}

// ---------------------------------------------------------------------------
// W[k][n] f32 -> transposed bf16 hi/lo: WT[n][k]. z=0: kW, z=1: vW.
// ---------------------------------------------------------------------------
__global__ __launch_bounds__(256) void convert_w(
    const float* __restrict__ kW, const float* __restrict__ vW,
    __hip_bfloat16* __restrict__ WkhiT, __hip_bfloat16* __restrict__ WkloT,
    __hip_bfloat16* __restrict__ WvhiT, __hip_bfloat16* __restrict__ WvloT) {
  __shared__ float tile[64][65];
  const int z = blockIdx.z;
  const float* __restrict__ W = z ? vW : kW;
  __hip_bfloat16* __restrict__ HiT = z ? WvhiT : WkhiT;
  __hip_bfloat16* __restrict__ LoT = z ? WvloT : WkloT;
  const int k0 = blockIdx.x * 64, n0 = blockIdx.y * 64;
  const int t = threadIdx.x;
#pragma unroll
  for (int s = 0; s < 16; s++) {
    int idx = t + s * 256;
    int r = idx >> 6, c = idx & 63;
    tile[r][c] = W[(long)(k0 + r) * FEAT + n0 + c];
  }
  __syncthreads();
#pragma unroll
  for (int s = 0; s < 16; s++) {
    int idx = t + s * 256;
    int a = idx >> 6, b = idx & 63;
    float w = tile[b][a];
    unsigned short h = f2bf_bits(w);
    unsigned short l = f2bf_bits(w - bf_bits2f(h));
    __builtin_memcpy(&HiT[(long)(n0 + a) * FEAT + k0 + b], &h, 2);
    __builtin_memcpy(&LoT[(long)(n0 + a) * FEAT + k0 + b], &l, 2);
  }
}

// ---------------------------------------------------------------------------
// kh/vh = A@W via split-bf16 MFMA: Ahi*Whi + Ahi*Wlo + Alo*Whi (~f32 accurate)
// Staging via async global_load_lds width=16.
// ---------------------------------------------------------------------------
__global__ __launch_bounds__(256) void mfma_dual(
    const __hip_bfloat16* __restrict__ Ahi, const __hip_bfloat16* __restrict__ Alo,
    const __hip_bfloat16* __restrict__ WkhiT, const __hip_bfloat16* __restrict__ WkloT,
    const __hip_bfloat16* __restrict__ WvhiT, const __hip_bfloat16* __restrict__ WvloT,
    float* __restrict__ kh, float* __restrict__ vh) {
  const int z = blockIdx.z;
  const __hip_bfloat16* __restrict__ WhiT = z ? WvhiT : WkhiT;
  const __hip_bfloat16* __restrict__ WloT = z ? WvloT : WkloT;
  float* __restrict__ outp = z ? vh : kh;
  const int ti = blockIdx.x, tj = blockIdx.y;
  __shared__ __align__(16) __hip_bfloat16 Ah[128 * 32];
  __shared__ __align__(16) __hip_bfloat16 Al[128 * 32];
  __shared__ __align__(16) __hip_bfloat16 Wh[128 * 32];
  __shared__ __align__(16) __hip_bfloat16 Wl[128 * 32];
  const int t = threadIdx.x;
  const int lane = t & 63, w = t >> 6;
  const int wm = (w >> 1) * 64, wn = (w & 1) * 64;
  const int quad = lane >> 4, ln = lane & 15;
  const int qr = quad * 8;
  floatx4 acc[4][4];
#pragma unroll
  for (int mi = 0; mi < 4; mi++)
#pragma unroll
    for (int ni = 0; ni < 4; ni++) acc[mi][ni] = (floatx4)0.f;
  for (int k0 = 0; k0 < FEAT; k0 += 32) {
    __syncthreads();
#pragma unroll
    for (int s = 0; s < 2; s++) {
      int c = t + s * 256;
      int row = c >> 2, off8 = (c & 3) * 8;
      int lo = row * 32 + off8;  // LDS elem offset == 8c -> byte 16c
      async_copy16(&Ahi[(long)(ti * 128 + row) * FEAT + k0 + off8], &Ah[lo]);
      async_copy16(&Alo[(long)(ti * 128 + row) * FEAT + k0 + off8], &Al[lo]);
      async_copy16(&WhiT[(long)(tj * 128 + row) * FEAT + k0 + off8], &Wh[lo]);
      async_copy16(&WloT[(long)(tj * 128 + row) * FEAT + k0 + off8], &Wl[lo]);
    }
    __syncthreads();
    short8 ah[4], al[4], bh[4], bl[4];
#pragma unroll
    for (int mi = 0; mi < 4; mi++) {
      ah[mi] = *(const short8*)&Ah[(wm + mi * 16 + ln) * 32 + qr];
      al[mi] = *(const short8*)&Al[(wm + mi * 16 + ln) * 32 + qr];
    }
#pragma unroll
    for (int ni = 0; ni < 4; ni++) {
      bh[ni] = *(const short8*)&Wh[(wn + ni * 16 + ln) * 32 + qr];
      bl[ni] = *(const short8*)&Wl[(wn + ni * 16 + ln) * 32 + qr];
    }
#pragma unroll
    for (int mi = 0; mi < 4; mi++)
#pragma unroll
      for (int ni = 0; ni < 4; ni++) {
        acc[mi][ni] = __builtin_amdgcn_mfma_f32_16x16x32_bf16(
            ah[mi], bh[ni], acc[mi][ni], 0, 0, 0);
        acc[mi][ni] = __builtin_amdgcn_mfma_f32_16x16x32_bf16(
            ah[mi], bl[ni], acc[mi][ni], 0, 0, 0);
        acc[mi][ni] = __builtin_amdgcn_mfma_f32_16x16x32_bf16(
            al[mi], bh[ni], acc[mi][ni], 0, 0, 0);
      }
  }
#pragma unroll
  for (int mi = 0; mi < 4; mi++)
#pragma unroll
    for (int ni = 0; ni < 4; ni++) {
      int cc = tj * 128 + wn + ni * 16 + ln;
#pragma unroll
      for (int reg = 0; reg < 4; reg++) {
        int r = ti * 128 + wm + mi * 16 + quad * 4 + reg;
        outp[(long)r * FEAT + cc] = acc[mi][ni][reg];
      }
    }
}

// ---------------------------------------------------------------------------
// cw[f][b] = sum_h kW[f][h] * rot[h][b]  (fp64)
// ---------------------------------------------------------------------------
__global__ __launch_bounds__(64) void cw_kernel(
    const float* __restrict__ kW, const float* __restrict__ rot,
    double* __restrict__ cw) {
  const int f = blockIdx.x;
  const int lane = threadIdx.x;
  double r0 = 0.0, r1 = 0.0;
  for (int h = lane; h < FEAT; h += 64) {
    double a = (double)kW[(long)f * FEAT + h];
    r0 += a * (double)rot[2 * h];
    r1 += a * (double)rot[2 * h + 1];
  }
#pragma unroll
  for (int off = 32; off > 0; off >>= 1) {
    r0 += __shfl_down(r0, off);
    r1 += __shfl_down(r1, off);
  }
  if (lane == 0) {
    cw[2 * f] = r0;
    cw[2 * f + 1] = r1;
  }
}

// ---------------------------------------------------------------------------
// buckets from EXACT inputs: rv = input @ cw in fp64; argmax([r0,r1,-r0,-r1])
// ---------------------------------------------------------------------------
__global__ __launch_bounds__(64) void rv_bucket_kernel(
    const float* __restrict__ input, const double* __restrict__ cw,
    int* __restrict__ buckets) {
  const int i = blockIdx.x;
  const int lane = threadIdx.x;
  double r0 = 0.0, r1 = 0.0;
  for (int f = lane; f < FEAT; f += 64) {
    double a = (double)input[(long)i * FEAT + f];
    r0 += a * cw[2 * f];
    r1 += a * cw[2 * f + 1];
  }
#pragma unroll
  for (int off = 32; off > 0; off >>= 1) {
    r0 += __shfl_down(r0, off);
    r1 += __shfl_down(r1, off);
  }
  if (lane == 0) {
    int b = 0;
    double best = r0;
    if (r1 > best)  { best = r1;  b = 1; }
    if (-r0 > best) { best = -r0; b = 2; }
    if (-r1 > best) { best = -r1; b = 3; }
    buckets[i] = b;
  }
}

// ---------------------------------------------------------------------------
// Stable counting sort by bucket (1 block, parallel Hillis-Steele scan).
// Also zeroes cmean (fused; runs before transpose's atomics).
// ---------------------------------------------------------------------------
__global__ __launch_bounds__(256) void sort_kernel(
    const int* __restrict__ buckets, int* __restrict__ perm,
    int* __restrict__ meta, float* __restrict__ cmean) {
  __shared__ int lc[4][256];
  __shared__ int sc[4][256];
  __shared__ int boff_sh[5];
  const int t = threadIdx.x;
  cmean[t] = 0.f;
  cmean[t + 256] = 0.f;
  const int base = t * 32;
  int c0 = 0, c1 = 0, c2 = 0, c3 = 0;
  for (int k = 0; k < 32; k++) {
    int b = buckets[base + k];
    c0 += (b == 0); c1 += (b == 1); c2 += (b == 2); c3 += (b == 3);
  }
  lc[0][t] = c0; lc[1][t] = c1; lc[2][t] = c2; lc[3][t] = c3;
  sc[0][t] = c0; sc[1][t] = c1; sc[2][t] = c2; sc[3][t] = c3;
  __syncthreads();
  for (int off = 1; off < 256; off <<= 1) {
    int a0 = (t >= off) ? sc[0][t - off] : 0;
    int a1 = (t >= off) ? sc[1][t - off] : 0;
    int a2 = (t >= off) ? sc[2][t - off] : 0;
    int a3 = (t >= off) ? sc[3][t - off] : 0;
    __syncthreads();
    sc[0][t] += a0; sc[1][t] += a1; sc[2][t] += a2; sc[3][t] += a3;
    __syncthreads();
  }
  if (t == 0) {
    int boff[5];
    boff[0] = 0;
    for (int b = 0; b < 4; b++) boff[b + 1] = boff[b] + sc[b][255];
    for (int b = 0; b < 5; b++) { meta[b] = boff[b]; boff_sh[b] = boff[b]; }
    long so = 0;
    int po = 0;
    for (int b = 0; b < 4; b++) {
      int tot = boff[b + 1] - boff[b];
      int pad = ((tot + 127) >> 7) << 7;
      meta[5 + b] = pad;
      meta[9 + b] = (int)so;
      meta[14 + b] = po;
      so += (long)pad * pad;
      po += pad;
    }
    meta[13] = (int)so;
    meta[18] = po;
    if (so > CAP_S)
      for (int b = 0; b < 4; b++) meta[5 + b] = 0;
  }
  __syncthreads();
  int s0 = boff_sh[0] + sc[0][t] - lc[0][t];
  int s1 = boff_sh[1] + sc[1][t] - lc[1][t];
  int s2 = boff_sh[2] + sc[2][t] - lc[2][t];
  int s3 = boff_sh[3] + sc[3][t] - lc[3][t];
  for (int k = 0; k < 32; k++) {
    int i = base + k;
    int b = buckets[i];
    int pos = (b == 0) ? s0++ : ((b == 1) ? s1++ : ((b == 2) ? s2++ : s3++));
    perm[pos] = i;
  }
}

// ---------------------------------------------------------------------------
// khp[g] = bf16(kh[perm[g]]); rows >= N zeroed.
// ---------------------------------------------------------------------------
__global__ __launch_bounds__(256) void gather_khp_kernel(
    const float* __restrict__ kh, const int* __restrict__ perm,
    __hip_bfloat16* __restrict__ khp) {
  const int g = blockIdx.x;
  const int t = threadIdx.x;
  if (g < N_NODES) {
    const int p = perm[g];
    const float2 v = *(const float2*)&kh[(long)p * FEAT + 2 * t];
    khp[(long)g * FEAT + 2 * t] = __float2bfloat16(v.x);
    khp[(long)g * FEAT + 2 * t + 1] = __float2bfloat16(v.y);
  } else {
    khp[(long)g * FEAT + 2 * t] = __float2bfloat16(0.f);
    khp[(long)g * FEAT + 2 * t + 1] = __float2bfloat16(0.f);
  }
}

// ---------------------------------------------------------------------------
// vhpT[f][poff_b + local] = bf16(vh[perm[boff_b + local]][f]); pads zeroed.
// Fused cmean column-sum accumulation (cmean pre-zeroed by sort_kernel).
// ---------------------------------------------------------------------------
__global__ __launch_bounds__(256) void transpose_vhpT_kernel(
    const float* __restrict__ vh, const int* __restrict__ perm,
    const int* __restrict__ meta, __hip_bfloat16* __restrict__ vhpT,
    float* __restrict__ cmean) {
  __shared__ float tile[64][65];
  __shared__ float cred[4][64];
  const int g0 = blockIdx.x * 64;
  const int f0 = blockIdx.y * 64;
  const int t = threadIdx.x;
#pragma unroll
  for (int s = 0; s < 16; s++) {
    int idx = t + s * 256;
    int r = idx >> 6, c = idx & 63;
    int pos = g0 + r;
    int b = (pos >= meta[15]) + (pos >= meta[16]) + (pos >= meta[17]);
    int local = pos - meta[14 + b];
    int n_b = meta[b + 1] - meta[b];
    float v = 0.f;
    if (local < n_b) v = vh[(long)perm[meta[b] + local] * FEAT + f0 + c];
    tile[r][c] = v;
  }
  __syncthreads();
  {
    const int c = t & 63, seg = t >> 6;
    float ps = 0.f;
#pragma unroll
    for (int rr = 0; rr < 16; rr++) ps += tile[seg * 16 + rr][c];
    cred[seg][c] = ps;
  }
  __syncthreads();
  if (t < 64)
    atomicAdd(&cmean[f0 + t],
              cred[0][t] + cred[1][t] + cred[2][t] + cred[3][t]);
#pragma unroll
  for (int s = 0; s < 16; s++) {
    int idx = t + s * 256;
    int fr = idx >> 6, gc = idx & 63;
    vhpT[(long)(f0 + fr) * VHPT_W + g0 + gc] = __float2bfloat16(tile[gc][fr]);
  }
}

// ---------------------------------------------------------------------------
// maskbits[g][jj] = (adj[perm[g]][perm[boff_b+jj]] > 0), bit-packed per 64.
// adj row staged via async global_load_lds.
// ---------------------------------------------------------------------------
__global__ __launch_bounds__(256) void maskpack_kernel(
    const int* __restrict__ adj, const int* __restrict__ perm,
    const int* __restrict__ meta, unsigned long long* __restrict__ maskbits) {
  __shared__ __align__(16) int adj_lds[N_NODES];
  const int g = blockIdx.x;
  const int t = threadIdx.x;
  const int b = (g >= meta[1]) + (g >= meta[2]) + (g >= meta[3]);
  const int boff = meta[b];
  const int n_b = meta[b + 1] - boff;
  const int padded = meta[5 + b];
  const int i = perm[g];
  const int* arow = adj + (long)i * N_NODES;
#pragma unroll
  for (int s = 0; s < 8; s++) {
    int idx = (t + s * 256) * 4;
    async_copy16(&arow[idx], &adj_lds[idx]);
  }
  __syncthreads();
  const int lane = t & 63, w = t >> 6;
  for (int jj0 = w * 64; jj0 < padded; jj0 += 256) {
    int jj = jj0 + lane;
    int pred = 0;
    if (jj < n_b) pred = adj_lds[perm[boff + jj]] > 0;
    unsigned long long mword = __ballot(pred);
    if (lane == 0) maskbits[(long)g * 128 + (jj0 >> 6)] = mword;
  }
}

// ---------------------------------------------------------------------------
// S tile = khp_b . khp_b^T (bf16 MFMA, async staging, BK=64 dual-panel).
// SYMMETRY: triangular-linearized grid covers ti <= tj only; epilogue routes
// acc through an LDS tile and writes BOTH orientations with coalesced 16B
// stores, applying the orientation-specific mask via u16 bit-selects.
// ---------------------------------------------------------------------------
__global__ __launch_bounds__(256) void s_gemm(
    const __hip_bfloat16* __restrict__ khp, const int* __restrict__ meta,
    const unsigned long long* __restrict__ maskbits,
    __hip_bfloat16* __restrict__ S) {
  const int b = blockIdx.z;
  const int padded = meta[5 + b];
  const int T = padded >> 7;
  const int pairs = (T * (T + 1)) >> 1;
  int L = blockIdx.x;
  if (L >= pairs) return;
  int ti = 0;
  while (L >= T - ti) { L -= T - ti; ti++; }
  const int tj = ti + L;
  const int boff = meta[b];
  const long soff = meta[9 + b];
  // 34,816 B: As/Bs (2 panels x 8 KB each) during main loop; Ct[128][136].
  __shared__ __align__(16) __hip_bfloat16 smem[128 * 136];
  __hip_bfloat16* As = smem;                  // [2][128*32]
  __hip_bfloat16* Bs = smem + 2 * 128 * 32;   // [2][128*32]
  const int t = threadIdx.x;
  const int lane = t & 63, w = t >> 6;
  const int wm = (w >> 1) * 64, wn = (w & 1) * 64;
  const int quad = lane >> 4, ln = lane & 15;
  const int qr = quad * 8;
  floatx4 acc[4][4];
#pragma unroll
  for (int mi = 0; mi < 4; mi++)
#pragma unroll
    for (int ni = 0; ni < 4; ni++) acc[mi][ni] = (floatx4)0.f;
  const long a_g0 = boff + ti * 128;
  const long b_g0 = boff + tj * 128;
  for (int k0 = 0; k0 < FEAT; k0 += 64) {
    __syncthreads();
#pragma unroll
    for (int p = 0; p < 2; p++)
#pragma unroll
      for (int s = 0; s < 2; s++) {
        int c = t + s * 256;
        int row = c >> 2, off8 = (c & 3) * 8;
        int lo = p * 4096 + row * 32 + off8;  // wave-uniform + lane*16
        async_copy16(&khp[(a_g0 + row) * FEAT + k0 + p * 32 + off8], &As[lo]);
        async_copy16(&khp[(b_g0 + row) * FEAT + k0 + p * 32 + off8], &Bs[lo]);
      }
    __syncthreads();
#pragma unroll
    for (int p = 0; p < 2; p++) {
      short8 af[4], bfr[4];
#pragma unroll
      for (int mi = 0; mi < 4; mi++)
        af[mi] =
            *(const short8*)&As[p * 4096 + (wm + mi * 16 + ln) * 32 + qr];
#pragma unroll
      for (int ni = 0; ni < 4; ni++)
        bfr[ni] =
            *(const short8*)&Bs[p * 4096 + (wn + ni * 16 + ln) * 32 + qr];
#pragma unroll
      for (int mi = 0; mi < 4; mi++)
#pragma unroll
        for (int ni = 0; ni < 4; ni++)
          acc[mi][ni] = __builtin_amdgcn_mfma_f32_16x16x32_bf16(
              af[mi], bfr[ni], acc[mi][ni], 0, 0, 0);
    }
  }
  // ---- epilogue: acc -> LDS tile (scaled bf16, unmasked) ----
  const float scale = 0.04419417382415922f;  // 1/sqrt(512)
  __syncthreads();  // As/Bs dead; reuse as Ct
  __hip_bfloat16* Ct = smem;  // [128][136]
#pragma unroll
  for (int mi = 0; mi < 4; mi++)
#pragma unroll
    for (int ni = 0; ni < 4; ni++) {
      int col = wn + ni * 16 + ln;
#pragma unroll
      for (int reg = 0; reg < 4; reg++) {
        int row = wm + mi * 16 + quad * 4 + reg;
        Ct[row * 136 + col] = __float2bfloat16(acc[mi][ni][reg] * scale);
      }
    }
  __syncthreads();
  const unsigned short negb = f2bf_bits(NEGV);
  // normal orientation: coalesced 16B stores of rows of the ti-block
#pragma unroll
  for (int i = 0; i < 8; i++) {
    int idx = t + i * 256;
    int rl = idx >> 4, c8 = (idx & 15) * 8;
    int rg = ti * 128 + rl;
    int cg = tj * 128 + c8;
    union { short8 v; unsigned short u[8]; } pk;
    pk.v = *(const short8*)&Ct[rl * 136 + c8];
    unsigned long long wbits = maskbits[(long)(boff + rg) * 128 + (cg >> 6)];
#pragma unroll
    for (int e = 0; e < 8; e++)
      if (!((wbits >> ((cg & 63) + e)) & 1ULL)) pk.u[e] = negb;
    *(short8*)&S[soff + (long)rg * padded + cg] = pk.v;
  }
  // mirrored orientation (tj-block rows), skipped on diagonal
  if (ti != tj) {
#pragma unroll
    for (int i = 0; i < 8; i++) {
      int idx = t + i * 256;
      int cl = idx >> 4, r8 = (idx & 15) * 8;
      int rg = tj * 128 + cl;   // output row (column of the computed tile)
      int cg = ti * 128 + r8;   // output col base
      union { short8 v; unsigned short u[8]; } pk;
#pragma unroll
      for (int e = 0; e < 8; e++) {
        __hip_bfloat16 hv = Ct[(r8 + e) * 136 + cl];
        __builtin_memcpy(&pk.u[e], &hv, 2);
      }
      unsigned long long wbits = maskbits[(long)(boff + rg) * 128 + (cg >> 6)];
#pragma unroll
      for (int e = 0; e < 8; e++)
        if (!((wbits >> ((cg & 63) + e)) & 1ULL)) pk.u[e] = negb;
      *(short8*)&S[soff + (long)rg * padded + cg] = pk.v;
    }
  }
}

// ---------------------------------------------------------------------------
// Row softmax — ONE WAVE PER ROW, TWO passes, normalization deferred to pv:
// pass 1 computes row max; pass 2 writes bf16(exp(x-m)) unnormalized and
// stores linv[g] = 1/sum. Empty rows: flag only (S row left as-is; pv's
// flag-select discards the finite garbage accumulator).
// ---------------------------------------------------------------------------
__global__ __launch_bounds__(256) void softmax_kernel(
    __hip_bfloat16* __restrict__ S, const int* __restrict__ meta,
    int* __restrict__ flags, float* __restrict__ linv) {
  const int g = blockIdx.x * 4 + (threadIdx.x >> 6);
  const int lane = threadIdx.x & 63;
  const int b = (g >= meta[1]) + (g >= meta[2]) + (g >= meta[3]);
  const int boff = meta[b];
  const int padded = meta[5 + b];
  const long soff = meta[9 + b];
  __hip_bfloat16* row = S + soff + (long)(g - boff) * padded;
  // pass 1: row max
  float m = -INFINITY;
  for (int j0 = lane * 8; j0 < padded; j0 += 512) {
    union { short8 v; unsigned short u[8]; } pk;
    pk.v = *(const short8*)&row[j0];
#pragma unroll
    for (int e = 0; e < 8; e++) m = fmaxf(m, bf_bits2f(pk.u[e]));
  }
#pragma unroll
  for (int off = 32; off > 0; off >>= 1) m = fmaxf(m, __shfl_xor(m, off));
  if (m < -8e15f) {  // empty (or degenerate) row
    if (lane == 0) {
      flags[g] = 1;
      linv[g] = 0.f;
    }
    return;
  }
  if (lane == 0) flags[g] = 0;
  // pass 2: write unnormalized exp, accumulate sum
  float sum = 0.f;
  for (int j0 = lane * 8; j0 < padded; j0 += 512) {
    union { short8 v; unsigned short u[8]; } pk;
    pk.v = *(const short8*)&row[j0];
#pragma unroll
    for (int e = 0; e < 8; e++) {
      float ex = expf(bf_bits2f(pk.u[e]) - m);
      sum += ex;
      pk.u[e] = f2bf_bits(ex);
    }
    *(short8*)&row[j0] = pk.v;
  }
#pragma unroll
  for (int off = 32; off > 0; off >>= 1) sum += __shfl_xor(sum, off);
  if (lane == 0) linv[g] = 1.f / sum;
}

// ---------------------------------------------------------------------------
// O tile = P_unnorm . vhp_b, 128 rows x 64 features, async staging, BK=64
// dual-panel. Epilogue: *linv (deferred softmax normalization), ELU,
// empty-row fallback, scatter to out[perm[g]].
// ---------------------------------------------------------------------------
__global__ __launch_bounds__(256) void pv_gemm(
    const __hip_bfloat16* __restrict__ S, const __hip_bfloat16* __restrict__ vhpT,
    const int* __restrict__ meta, const int* __restrict__ perm,
    const int* __restrict__ flags, const float* __restrict__ linv,
    const float* __restrict__ cmean, float* __restrict__ out) {
  const int b = blockIdx.z;
  const int padded = meta[5 + b];
  const int ti = blockIdx.x;
  if (ti * 128 >= padded) return;
  const int boff = meta[b];
  const int n_b = meta[b + 1] - boff;
  const long soff = meta[9 + b];
  const int poff = meta[14 + b];
  const int f0 = blockIdx.y * 64;
  __shared__ __align__(16) __hip_bfloat16 As[2 * 128 * 32];
  __shared__ __align__(16) __hip_bfloat16 Bs[2 * 64 * 32];
  const int t = threadIdx.x;
  const int lane = t & 63, w = t >> 6;
  const int wm = w * 32;
  const int quad = lane >> 4, ln = lane & 15;
  const int qr = quad * 8;
  floatx4 acc[2][4];
#pragma unroll
  for (int mi = 0; mi < 2; mi++)
#pragma unroll
    for (int ni = 0; ni < 4; ni++) acc[mi][ni] = (floatx4)0.f;
  const long r0 = (long)ti * 128;
  for (int k0 = 0; k0 < padded; k0 += 64) {
    __syncthreads();
#pragma unroll
    for (int p = 0; p < 2; p++) {
#pragma unroll
      for (int s = 0; s < 2; s++) {
        int c = t + s * 256;
        int row = c >> 2, off8 = (c & 3) * 8;
        async_copy16(&S[soff + (r0 + row) * padded + k0 + p * 32 + off8],
                     &As[p * 4096 + row * 32 + off8]);
      }
      {
        int row = t >> 2, off8 = (t & 3) * 8;
        async_copy16(
            &vhpT[(long)(f0 + row) * VHPT_W + poff + k0 + p * 32 + off8],
            &Bs[p * 2048 + row * 32 + off8]);
      }
    }
    __syncthreads();
#pragma unroll
    for (int p = 0; p < 2; p++) {
      short8 af[2], bfr[4];
#pragma unroll
      for (int mi = 0; mi < 2; mi++)
        af[mi] =
            *(const short8*)&As[p * 4096 + (wm + mi * 16 + ln) * 32 + qr];
#pragma unroll
      for (int ni = 0; ni < 4; ni++)
        bfr[ni] = *(const short8*)&Bs[p * 2048 + (ni * 16 + ln) * 32 + qr];
#pragma unroll
      for (int mi = 0; mi < 2; mi++)
#pragma unroll
        for (int ni = 0; ni < 4; ni++)
          acc[mi][ni] = __builtin_amdgcn_mfma_f32_16x16x32_bf16(
              af[mi], bfr[ni], acc[mi][ni], 0, 0, 0);
    }
  }
#pragma unroll
  for (int mi = 0; mi < 2; mi++) {
#pragma unroll
    for (int reg = 0; reg < 4; reg++) {
      int r = ti * 128 + wm + mi * 16 + quad * 4 + reg;
      if (r < n_b) {
        int g = boff + r;
        int node = perm[g];
        int fl = flags[g];
        float li = linv[g];
#pragma unroll
        for (int ni = 0; ni < 4; ni++) {
          int fc = f0 + ni * 16 + ln;
          float v = fl ? cmean[fc] * (1.f / (float)N_NODES)
                       : acc[mi][ni][reg] * li;
          v = v > 0.f ? v : expm1f(v);
          out[(long)node * FEAT + fc] = v;
        }
      }
    }
  }
}

// ===========================================================================
// Slow-path fallback (only if ws_size < WS_NEEDED): round-1 implementation.
// ===========================================================================
__global__ __launch_bounds__(256) void gemm_dual(
    const float* __restrict__ A, const float* __restrict__ Wk,
    const float* __restrict__ Wv, float* __restrict__ kh,
    float* __restrict__ vh) {
  __shared__ float As[32][33];
  __shared__ float Bk[32][33];
  __shared__ float Bv[32][33];
  const int tid = threadIdx.x;
  const int row0 = blockIdx.x * 32;
  const int col0 = blockIdx.y * 32;
  const int tx = tid & 15, ty = tid >> 4;
  float ck00 = 0.f, ck01 = 0.f, ck10 = 0.f, ck11 = 0.f;
  float cv00 = 0.f, cv01 = 0.f, cv10 = 0.f, cv11 = 0.f;
  for (int kt = 0; kt < FEAT; kt += 32) {
#pragma unroll
    for (int t = 0; t < 4; t++) {
      int e = tid + t * 256;
      int r = e >> 5, c = e & 31;
      As[r][c] = A[(long)(row0 + r) * FEAT + kt + c];
      Bk[r][c] = Wk[(long)(kt + r) * FEAT + col0 + c];
      Bv[r][c] = Wv[(long)(kt + r) * FEAT + col0 + c];
    }
    __syncthreads();
#pragma unroll
    for (int kk = 0; kk < 32; kk++) {
      float a0 = As[ty * 2][kk], a1 = As[ty * 2 + 1][kk];
      float bk0 = Bk[kk][tx * 2], bk1 = Bk[kk][tx * 2 + 1];
      float bv0 = Bv[kk][tx * 2], bv1 = Bv[kk][tx * 2 + 1];
      ck00 += a0 * bk0; ck01 += a0 * bk1;
      ck10 += a1 * bk0; ck11 += a1 * bk1;
      cv00 += a0 * bv0; cv01 += a0 * bv1;
      cv10 += a1 * bv0; cv11 += a1 * bv1;
    }
    __syncthreads();
  }
  const int r0 = row0 + ty * 2, c0 = col0 + tx * 2;
  kh[(long)r0 * FEAT + c0] = ck00;       kh[(long)r0 * FEAT + c0 + 1] = ck01;
  kh[(long)(r0 + 1) * FEAT + c0] = ck10; kh[(long)(r0 + 1) * FEAT + c0 + 1] = ck11;
  vh[(long)r0 * FEAT + c0] = cv00;       vh[(long)r0 * FEAT + c0 + 1] = cv01;
  vh[(long)(r0 + 1) * FEAT + c0] = cv10; vh[(long)(r0 + 1) * FEAT + c0 + 1] = cv11;
}

__global__ __launch_bounds__(64) void bucket_kernel(
    const float* __restrict__ kh, const float* __restrict__ rot,
    int* __restrict__ buckets) {
  const int i = blockIdx.x;
  const int lane = threadIdx.x;
  double r0 = 0.0, r1 = 0.0;
  for (int h = lane; h < FEAT; h += 64) {
    double a = (double)kh[(long)i * FEAT + h];
    r0 += a * (double)rot[2 * h];
    r1 += a * (double)rot[2 * h + 1];
  }
#pragma unroll
  for (int off = 32; off > 0; off >>= 1) {
    r0 += __shfl_down(r0, off);
    r1 += __shfl_down(r1, off);
  }
  if (lane == 0) {
    int b = 0;
    double best = r0;
    if (r1 > best)  { best = r1;  b = 1; }
    if (-r0 > best) { best = -r0; b = 2; }
    if (-r1 > best) { best = -r1; b = 3; }
    buckets[i] = b;
  }
}

__global__ __launch_bounds__(256) void attn_kernel(
    const float* __restrict__ kh, const float* __restrict__ vh,
    const int* __restrict__ adj, const int* __restrict__ buckets,
    float* __restrict__ out) {
  __shared__ float khi[FEAT];
  __shared__ float pbuf[N_NODES];
  __shared__ unsigned short jlist[N_NODES];
  __shared__ int cnt_sh;
  __shared__ float red[256];
  const int i = blockIdx.x;
  const int tid = threadIdx.x;
  if (tid == 0) cnt_sh = 0;
  for (int k = tid; k < FEAT; k += 256) khi[k] = kh[(long)i * FEAT + k];
  const int mybucket = buckets[i];
  __syncthreads();
  const int* adjrow = adj + (long)i * N_NODES;
  for (int j = tid; j < N_NODES; j += 256) {
    if (adjrow[j] > 0 && buckets[j] == mybucket) {
      int idx = atomicAdd(&cnt_sh, 1);
      jlist[idx] = (unsigned short)j;
    }
  }
  __syncthreads();
  const int cnt = cnt_sh;
  float mloc = -INFINITY;
  for (int idx = tid; idx < cnt; idx += 256) {
    int j = jlist[idx];
    const float4* kj = (const float4*)(kh + (long)j * FEAT);
    const float4* ki = (const float4*)khi;
    float acc = 0.f;
#pragma unroll 8
    for (int k = 0; k < FEAT / 4; k++) {
      float4 a = ki[k];
      float4 b = kj[k];
      acc += a.x * b.x + a.y * b.y + a.z * b.z + a.w * b.w;
    }
    float s = acc * 0.04419417382415922f;
    pbuf[idx] = s;
    mloc = fmaxf(mloc, s);
  }
  red[tid] = mloc;
  __syncthreads();
#pragma unroll
  for (int off = 128; off > 0; off >>= 1) {
    if (tid < off) red[tid] = fmaxf(red[tid], red[tid + off]);
    __syncthreads();
  }
  const float m = red[0];
  __syncthreads();
  float lloc = 0.f;
  for (int idx = tid; idx < cnt; idx += 256) {
    float p = expf(pbuf[idx] - m);
    pbuf[idx] = p;
    lloc += p;
  }
  red[tid] = lloc;
  __syncthreads();
#pragma unroll
  for (int off = 128; off > 0; off >>= 1) {
    if (tid < off) red[tid] += red[tid + off];
    __syncthreads();
  }
  const float l = red[0];
  __syncthreads();
  const int f = 2 * tid;
  float acc0 = 0.f, acc1 = 0.f;
  if (cnt > 0) {
#pragma unroll 4
    for (int idx = 0; idx < cnt; idx++) {
      int j = jlist[idx];
      float p = pbuf[idx];
      float2 v = *(const float2*)(vh + (long)j * FEAT + f);
      acc0 += p * v.x;
      acc1 += p * v.y;
    }
    float invl = 1.f / l;
    acc0 *= invl;
    acc1 *= invl;
  } else {
    for (int j = 0; j < N_NODES; j++) {
      float2 v = *(const float2*)(vh + (long)j * FEAT + f);
      acc0 += v.x;
      acc1 += v.y;
    }
    acc0 *= (1.f / (float)N_NODES);
    acc1 *= (1.f / (float)N_NODES);
  }
  acc0 = acc0 > 0.f ? acc0 : expm1f(acc0);
  acc1 = acc1 > 0.f ? acc1 : expm1f(acc1);
  *(float2*)(out + (long)i * FEAT + f) = make_float2(acc0, acc1);
}

extern "C" void kernel_launch(void* const* d_in, const int* in_sizes, int n_in,
                              void* d_out, int out_size, void* d_ws,
                              size_t ws_size, hipStream_t stream) {
  const float* input = (const float*)d_in[0];
  const int* adj = (const int*)d_in[1];
  const float* rot = (const float*)d_in[2];
  const float* kW = (const float*)d_in[3];
  const float* vW = (const float*)d_in[4];
  float* out = (float*)d_out;

  char* ws = (char*)d_ws;

  if (ws_size >= WS_NEEDED) {
    float* kh = (float*)(ws + OFF_KH);
    float* vh = (float*)(ws + OFF_VH);
    __hip_bfloat16* khp = (__hip_bfloat16*)(ws + OFF_KHP);
    __hip_bfloat16* vhpT = (__hip_bfloat16*)(ws + OFF_VHPT);
    unsigned long long* maskbits = (unsigned long long*)(ws + OFF_MASK);
    __hip_bfloat16* S = (__hip_bfloat16*)(ws + OFF_S);
    int* perm = (int*)(ws + OFF_PERM);
    int* flags = (int*)(ws + OFF_FLAGS);
    int* buckets = (int*)(ws + OFF_BUCK);
    int* meta = (int*)(ws + OFF_META);
    float* cmean = (float*)(ws + OFF_CMEAN);
    float* linv = (float*)(ws + OFF_LINV);
    __hip_bfloat16* Ahi = (__hip_bfloat16*)(ws + OFF_AHI);
    __hip_bfloat16* Alo = (__hip_bfloat16*)(ws + OFF_ALO);
    __hip_bfloat16* WkhiT = (__hip_bfloat16*)(ws + OFF_WKHI);
    __hip_bfloat16* WkloT = (__hip_bfloat16*)(ws + OFF_WKLO);
    __hip_bfloat16* WvhiT = (__hip_bfloat16*)(ws + OFF_WVHI);
    __hip_bfloat16* WvloT = (__hip_bfloat16*)(ws + OFF_WVLO);
    double* cw = (double*)(ws + OFF_CW);

    convert_input<<<4096, 256, 0, stream>>>(input, Ahi, Alo);
    convert_w<<<dim3(8, 8, 2), 256, 0, stream>>>(kW, vW, WkhiT, WkloT, WvhiT,
                                                 WvloT);
    mfma_dual<<<dim3(64, 4, 2), 256, 0, stream>>>(Ahi, Alo, WkhiT, WkloT,
                                                  WvhiT, WvloT, kh, vh);
    cw_kernel<<<512, 64, 0, stream>>>(kW, rot, cw);
    rv_bucket_kernel<<<N_NODES, 64, 0, stream>>>(input, cw, buckets);
    sort_kernel<<<1, 256, 0, stream>>>(buckets, perm, meta, cmean);
    gather_khp_kernel<<<N_NODES + 128, 256, 0, stream>>>(kh, perm, khp);
    transpose_vhpT_kernel<<<dim3(VHPT_W / 64, FEAT / 64), 256, 0, stream>>>(
        vh, perm, meta, vhpT, cmean);
    maskpack_kernel<<<N_NODES, 256, 0, stream>>>(adj, perm, meta, maskbits);
    s_gemm<<<dim3(2080, 1, 4), 256, 0, stream>>>(khp, meta, maskbits, S);
    softmax_kernel<<<N_NODES / 4, 256, 0, stream>>>(S, meta, flags, linv);
    pv_gemm<<<dim3(64, 8, 4), 256, 0, stream>>>(S, vhpT, meta, perm, flags,
                                                linv, cmean, out);
  } else {
    float* kh = (float*)(ws + 0UL);
    float* vh = (float*)(ws + 16777216UL);
    int* buckets = (int*)(ws + 33554432UL);
    dim3 gemm_grid(N_NODES / 32, FEAT / 32);
    gemm_dual<<<gemm_grid, 256, 0, stream>>>(input, kW, vW, kh, vh);
    bucket_kernel<<<N_NODES, 64, 0, stream>>>(kh, rot, buckets);
    attn_kernel<<<N_NODES, 256, 0, stream>>>(kh, vh, adj, buckets, out);
  }
}

// Round 12
// 588.549 us; speedup vs baseline: 1.0132x; 1.0132x over previous
//
#include <hip/hip_runtime.h>
#include <hip/hip_bf16.h>
#include <math.h>

#define N_NODES 8192
#define FEAT 512
#define NEGV -9e15f
#define VHPT_W 8704

typedef __attribute__((ext_vector_type(8))) short short8;
typedef __attribute__((ext_vector_type(4))) float floatx4;

// ---- workspace layout (bytes) ----
#define OFF_KH    0UL          // f32 kh [8192][512]
#define OFF_VH    16777216UL   // f32 vh [8192][512]
#define OFF_KHP   33554432UL   // bf16 [8320][512]
#define OFF_VHPT  42074112UL   // bf16 [512][8704]  (padded-position columns)
#define OFF_MASK  50987008UL   // u64 [8192][128]; head reused early for cw (f64[1024])
#define OFF_S     59375616UL   // bf16 S, cap 25165824 elems; head reused early for Ahi/Alo/W*T
#define OFF_PERM  109707264UL
#define OFF_FLAGS 109740032UL
#define OFF_BUCK  109772800UL
#define OFF_META  109805568UL  // ints: [0..4]=boff [5..8]=padded [9..13]=soff(+tot) [14..18]=poff
#define OFF_CMEAN 109806592UL
#define WS_NEEDED 109808640UL
#define CAP_S     25165824L

// aliased (early-lifetime) buffers inside the S region:
#define OFF_AHI   (OFF_S)                 // bf16 [8192][512]
#define OFF_ALO   (OFF_S + 8388608UL)
#define OFF_WKHI  (OFF_S + 16777216UL)    // bf16 [512][512] transposed
#define OFF_WKLO  (OFF_S + 17301504UL)
#define OFF_WVHI  (OFF_S + 17825792UL)
#define OFF_WVLO  (OFF_S + 18350080UL)
#define OFF_CW    (OFF_MASK)              // f64 [512][2] (dead before maskpack)

static __device__ __forceinline__ unsigned short f2bf_bits(float x) {
  __hip_bfloat16 h = __float2bfloat16(x);
  unsigned short u;
  __builtin_memcpy(&u, &h, 2);
  return u;
}
static __device__ __forceinline__ float bf_bits2f(unsigned short u) {
  __hip_bfloat16 h;
  __builtin_memcpy(&h, &u, 2);
  return __bfloat162float(h);
}

// Async 16B/lane global->LDS copy (global_load_lds_dwordx4). LDS side must be
// wave-uniform base + lane*16 — all call sites below satisfy this.
static __device__ __forceinline__ void async_copy16(const void* gptr,
                                                    void* lptr) {
  __builtin_amdgcn_global_load_lds(
      (const __attribute__((address_space(1))) unsigned int*)gptr,
      (__attribute__((address_space(3))) unsigned int*)lptr, 16, 0, 0);
}

// ---------------------------------------------------------------------------
// input f32 -> bf16 hi/lo split (hi = bf16(x), lo = bf16(x - hi))
// ---------------------------------------------------------------------------
__global__ __launch_bounds__(256) void convert_input(
    const float* __restrict__ A, __hip_bfloat16* __restrict__ Ahi,
    __hip_bfloat16* __restrict__ Alo) {
  const long idx = ((long)blockIdx.x * 256 + threadIdx.x) * 4;
  const float4 v = *(const float4*)&A[idx];
  const float vv[4] = {v.x, v.y, v.z, v.w};
  ushort4 hi, lo;
  unsigned short* hp = (unsigned short*)&hi;
  unsigned short* lp = (unsigned short*)&lo;
#pragma unroll
  for (int e = 0; e < 4; e++) {
    unsigned short h = f2bf_bits(vv[e]);
    hp[e] = h;
    lp[e] = f2bf_bits(vv[e] - bf_bits2f(h));
  }
  *(ushort4*)&Ahi[idx] = hi;
  *(ushort4*)&Alo[idx] = lo;
}

// ---------------------------------------------------------------------------
// W[k][n] f32 -> transposed bf16 hi/lo: WT[n][k]. z=0: kW, z=1: vW.
// ---------------------------------------------------------------------------
__global__ __launch_bounds__(256) void convert_w(
    const float* __restrict__ kW, const float* __restrict__ vW,
    __hip_bfloat16* __restrict__ WkhiT, __hip_bfloat16* __restrict__ WkloT,
    __hip_bfloat16* __restrict__ WvhiT, __hip_bfloat16* __restrict__ WvloT) {
  __shared__ float tile[64][65];
  const int z = blockIdx.z;
  const float* __restrict__ W = z ? vW : kW;
  __hip_bfloat16* __restrict__ HiT = z ? WvhiT : WkhiT;
  __hip_bfloat16* __restrict__ LoT = z ? WvloT : WkloT;
  const int k0 = blockIdx.x * 64, n0 = blockIdx.y * 64;
  const int t = threadIdx.x;
#pragma unroll
  for (int s = 0; s < 16; s++) {
    int idx = t + s * 256;
    int r = idx >> 6, c = idx & 63;
    tile[r][c] = W[(long)(k0 + r) * FEAT + n0 + c];
  }
  __syncthreads();
#pragma unroll
  for (int s = 0; s < 16; s++) {
    int idx = t + s * 256;
    int a = idx >> 6, b = idx & 63;
    float w = tile[b][a];
    unsigned short h = f2bf_bits(w);
    unsigned short l = f2bf_bits(w - bf_bits2f(h));
    __builtin_memcpy(&HiT[(long)(n0 + a) * FEAT + k0 + b], &h, 2);
    __builtin_memcpy(&LoT[(long)(n0 + a) * FEAT + k0 + b], &l, 2);
  }
}

// ---------------------------------------------------------------------------
// kh/vh = A@W via split-bf16 MFMA: Ahi*Whi + Ahi*Wlo + Alo*Whi (~f32 accurate)
// Staging via async global_load_lds width=16.
// ---------------------------------------------------------------------------
__global__ __launch_bounds__(256) void mfma_dual(
    const __hip_bfloat16* __restrict__ Ahi, const __hip_bfloat16* __restrict__ Alo,
    const __hip_bfloat16* __restrict__ WkhiT, const __hip_bfloat16* __restrict__ WkloT,
    const __hip_bfloat16* __restrict__ WvhiT, const __hip_bfloat16* __restrict__ WvloT,
    float* __restrict__ kh, float* __restrict__ vh) {
  const int z = blockIdx.z;
  const __hip_bfloat16* __restrict__ WhiT = z ? WvhiT : WkhiT;
  const __hip_bfloat16* __restrict__ WloT = z ? WvloT : WkloT;
  float* __restrict__ outp = z ? vh : kh;
  const int ti = blockIdx.x, tj = blockIdx.y;
  __shared__ __align__(16) __hip_bfloat16 Ah[128 * 32];
  __shared__ __align__(16) __hip_bfloat16 Al[128 * 32];
  __shared__ __align__(16) __hip_bfloat16 Wh[128 * 32];
  __shared__ __align__(16) __hip_bfloat16 Wl[128 * 32];
  const int t = threadIdx.x;
  const int lane = t & 63, w = t >> 6;
  const int wm = (w >> 1) * 64, wn = (w & 1) * 64;
  const int quad = lane >> 4, ln = lane & 15;
  const int qr = quad * 8;
  floatx4 acc[4][4];
#pragma unroll
  for (int mi = 0; mi < 4; mi++)
#pragma unroll
    for (int ni = 0; ni < 4; ni++) acc[mi][ni] = (floatx4)0.f;
  for (int k0 = 0; k0 < FEAT; k0 += 32) {
    __syncthreads();
#pragma unroll
    for (int s = 0; s < 2; s++) {
      int c = t + s * 256;
      int row = c >> 2, off8 = (c & 3) * 8;
      int lo = row * 32 + off8;  // LDS elem offset == 8c -> byte 16c
      async_copy16(&Ahi[(long)(ti * 128 + row) * FEAT + k0 + off8], &Ah[lo]);
      async_copy16(&Alo[(long)(ti * 128 + row) * FEAT + k0 + off8], &Al[lo]);
      async_copy16(&WhiT[(long)(tj * 128 + row) * FEAT + k0 + off8], &Wh[lo]);
      async_copy16(&WloT[(long)(tj * 128 + row) * FEAT + k0 + off8], &Wl[lo]);
    }
    __syncthreads();
    short8 ah[4], al[4], bh[4], bl[4];
#pragma unroll
    for (int mi = 0; mi < 4; mi++) {
      ah[mi] = *(const short8*)&Ah[(wm + mi * 16 + ln) * 32 + qr];
      al[mi] = *(const short8*)&Al[(wm + mi * 16 + ln) * 32 + qr];
    }
#pragma unroll
    for (int ni = 0; ni < 4; ni++) {
      bh[ni] = *(const short8*)&Wh[(wn + ni * 16 + ln) * 32 + qr];
      bl[ni] = *(const short8*)&Wl[(wn + ni * 16 + ln) * 32 + qr];
    }
#pragma unroll
    for (int mi = 0; mi < 4; mi++)
#pragma unroll
      for (int ni = 0; ni < 4; ni++) {
        acc[mi][ni] = __builtin_amdgcn_mfma_f32_16x16x32_bf16(
            ah[mi], bh[ni], acc[mi][ni], 0, 0, 0);
        acc[mi][ni] = __builtin_amdgcn_mfma_f32_16x16x32_bf16(
            ah[mi], bl[ni], acc[mi][ni], 0, 0, 0);
        acc[mi][ni] = __builtin_amdgcn_mfma_f32_16x16x32_bf16(
            al[mi], bh[ni], acc[mi][ni], 0, 0, 0);
      }
  }
#pragma unroll
  for (int mi = 0; mi < 4; mi++)
#pragma unroll
    for (int ni = 0; ni < 4; ni++) {
      int cc = tj * 128 + wn + ni * 16 + ln;
#pragma unroll
      for (int reg = 0; reg < 4; reg++) {
        int r = ti * 128 + wm + mi * 16 + quad * 4 + reg;
        outp[(long)r * FEAT + cc] = acc[mi][ni][reg];
      }
    }
}

// ---------------------------------------------------------------------------
// cw[f][b] = sum_h kW[f][h] * rot[h][b]  (fp64)
// ---------------------------------------------------------------------------
__global__ __launch_bounds__(64) void cw_kernel(
    const float* __restrict__ kW, const float* __restrict__ rot,
    double* __restrict__ cw) {
  const int f = blockIdx.x;
  const int lane = threadIdx.x;
  double r0 = 0.0, r1 = 0.0;
  for (int h = lane; h < FEAT; h += 64) {
    double a = (double)kW[(long)f * FEAT + h];
    r0 += a * (double)rot[2 * h];
    r1 += a * (double)rot[2 * h + 1];
  }
#pragma unroll
  for (int off = 32; off > 0; off >>= 1) {
    r0 += __shfl_down(r0, off);
    r1 += __shfl_down(r1, off);
  }
  if (lane == 0) {
    cw[2 * f] = r0;
    cw[2 * f + 1] = r1;
  }
}

// ---------------------------------------------------------------------------
// buckets from EXACT inputs: rv = input @ cw in fp64; argmax([r0,r1,-r0,-r1])
// ---------------------------------------------------------------------------
__global__ __launch_bounds__(64) void rv_bucket_kernel(
    const float* __restrict__ input, const double* __restrict__ cw,
    int* __restrict__ buckets) {
  const int i = blockIdx.x;
  const int lane = threadIdx.x;
  double r0 = 0.0, r1 = 0.0;
  for (int f = lane; f < FEAT; f += 64) {
    double a = (double)input[(long)i * FEAT + f];
    r0 += a * cw[2 * f];
    r1 += a * cw[2 * f + 1];
  }
#pragma unroll
  for (int off = 32; off > 0; off >>= 1) {
    r0 += __shfl_down(r0, off);
    r1 += __shfl_down(r1, off);
  }
  if (lane == 0) {
    int b = 0;
    double best = r0;
    if (r1 > best)  { best = r1;  b = 1; }
    if (-r0 > best) { best = -r0; b = 2; }
    if (-r1 > best) { best = -r1; b = 3; }
    buckets[i] = b;
  }
}

// ---------------------------------------------------------------------------
// Stable counting sort by bucket (1 block, parallel Hillis-Steele scan).
// Also zeroes cmean (fused; runs before transpose's atomics).
// ---------------------------------------------------------------------------
__global__ __launch_bounds__(256) void sort_kernel(
    const int* __restrict__ buckets, int* __restrict__ perm,
    int* __restrict__ meta, float* __restrict__ cmean) {
  __shared__ int lc[4][256];
  __shared__ int sc[4][256];
  __shared__ int boff_sh[5];
  const int t = threadIdx.x;
  cmean[t] = 0.f;
  cmean[t + 256] = 0.f;
  const int base = t * 32;
  int c0 = 0, c1 = 0, c2 = 0, c3 = 0;
  for (int k = 0; k < 32; k++) {
    int b = buckets[base + k];
    c0 += (b == 0); c1 += (b == 1); c2 += (b == 2); c3 += (b == 3);
  }
  lc[0][t] = c0; lc[1][t] = c1; lc[2][t] = c2; lc[3][t] = c3;
  sc[0][t] = c0; sc[1][t] = c1; sc[2][t] = c2; sc[3][t] = c3;
  __syncthreads();
  for (int off = 1; off < 256; off <<= 1) {
    int a0 = (t >= off) ? sc[0][t - off] : 0;
    int a1 = (t >= off) ? sc[1][t - off] : 0;
    int a2 = (t >= off) ? sc[2][t - off] : 0;
    int a3 = (t >= off) ? sc[3][t - off] : 0;
    __syncthreads();
    sc[0][t] += a0; sc[1][t] += a1; sc[2][t] += a2; sc[3][t] += a3;
    __syncthreads();
  }
  if (t == 0) {
    int boff[5];
    boff[0] = 0;
    for (int b = 0; b < 4; b++) boff[b + 1] = boff[b] + sc[b][255];
    for (int b = 0; b < 5; b++) { meta[b] = boff[b]; boff_sh[b] = boff[b]; }
    long so = 0;
    int po = 0;
    for (int b = 0; b < 4; b++) {
      int tot = boff[b + 1] - boff[b];
      int pad = ((tot + 127) >> 7) << 7;
      meta[5 + b] = pad;
      meta[9 + b] = (int)so;
      meta[14 + b] = po;
      so += (long)pad * pad;
      po += pad;
    }
    meta[13] = (int)so;
    meta[18] = po;
    if (so > CAP_S)
      for (int b = 0; b < 4; b++) meta[5 + b] = 0;
  }
  __syncthreads();
  int s0 = boff_sh[0] + sc[0][t] - lc[0][t];
  int s1 = boff_sh[1] + sc[1][t] - lc[1][t];
  int s2 = boff_sh[2] + sc[2][t] - lc[2][t];
  int s3 = boff_sh[3] + sc[3][t] - lc[3][t];
  for (int k = 0; k < 32; k++) {
    int i = base + k;
    int b = buckets[i];
    int pos = (b == 0) ? s0++ : ((b == 1) ? s1++ : ((b == 2) ? s2++ : s3++));
    perm[pos] = i;
  }
}

// ---------------------------------------------------------------------------
// khp[g] = bf16(kh[perm[g]]); rows >= N zeroed.
// ---------------------------------------------------------------------------
__global__ __launch_bounds__(256) void gather_khp_kernel(
    const float* __restrict__ kh, const int* __restrict__ perm,
    __hip_bfloat16* __restrict__ khp) {
  const int g = blockIdx.x;
  const int t = threadIdx.x;
  if (g < N_NODES) {
    const int p = perm[g];
    const float2 v = *(const float2*)&kh[(long)p * FEAT + 2 * t];
    khp[(long)g * FEAT + 2 * t] = __float2bfloat16(v.x);
    khp[(long)g * FEAT + 2 * t + 1] = __float2bfloat16(v.y);
  } else {
    khp[(long)g * FEAT + 2 * t] = __float2bfloat16(0.f);
    khp[(long)g * FEAT + 2 * t + 1] = __float2bfloat16(0.f);
  }
}

// ---------------------------------------------------------------------------
// vhpT[f][poff_b + local] = bf16(vh[perm[boff_b + local]][f]); pads zeroed.
// Fused cmean column-sum accumulation (cmean pre-zeroed by sort_kernel).
// ---------------------------------------------------------------------------
__global__ __launch_bounds__(256) void transpose_vhpT_kernel(
    const float* __restrict__ vh, const int* __restrict__ perm,
    const int* __restrict__ meta, __hip_bfloat16* __restrict__ vhpT,
    float* __restrict__ cmean) {
  __shared__ float tile[64][65];
  __shared__ float cred[4][64];
  const int g0 = blockIdx.x * 64;
  const int f0 = blockIdx.y * 64;
  const int t = threadIdx.x;
#pragma unroll
  for (int s = 0; s < 16; s++) {
    int idx = t + s * 256;
    int r = idx >> 6, c = idx & 63;
    int pos = g0 + r;
    int b = (pos >= meta[15]) + (pos >= meta[16]) + (pos >= meta[17]);
    int local = pos - meta[14 + b];
    int n_b = meta[b + 1] - meta[b];
    float v = 0.f;
    if (local < n_b) v = vh[(long)perm[meta[b] + local] * FEAT + f0 + c];
    tile[r][c] = v;
  }
  __syncthreads();
  {
    const int c = t & 63, seg = t >> 6;
    float ps = 0.f;
#pragma unroll
    for (int rr = 0; rr < 16; rr++) ps += tile[seg * 16 + rr][c];
    cred[seg][c] = ps;
  }
  __syncthreads();
  if (t < 64)
    atomicAdd(&cmean[f0 + t],
              cred[0][t] + cred[1][t] + cred[2][t] + cred[3][t]);
#pragma unroll
  for (int s = 0; s < 16; s++) {
    int idx = t + s * 256;
    int fr = idx >> 6, gc = idx & 63;
    vhpT[(long)(f0 + fr) * VHPT_W + g0 + gc] = __float2bfloat16(tile[gc][fr]);
  }
}

// ---------------------------------------------------------------------------
// maskbits[g][jj] = (adj[perm[g]][perm[boff_b+jj]] > 0), bit-packed per 64.
// ---------------------------------------------------------------------------
__global__ __launch_bounds__(256) void maskpack_kernel(
    const int* __restrict__ adj, const int* __restrict__ perm,
    const int* __restrict__ meta, unsigned long long* __restrict__ maskbits) {
  __shared__ int adj_lds[N_NODES];
  const int g = blockIdx.x;
  const int t = threadIdx.x;
  const int b = (g >= meta[1]) + (g >= meta[2]) + (g >= meta[3]);
  const int boff = meta[b];
  const int n_b = meta[b + 1] - boff;
  const int padded = meta[5 + b];
  const int i = perm[g];
  const int* arow = adj + (long)i * N_NODES;
#pragma unroll
  for (int s = 0; s < 8; s++) {
    int idx = (t + s * 256) * 4;
    *(int4*)&adj_lds[idx] = *(const int4*)&arow[idx];
  }
  __syncthreads();
  const int lane = t & 63, w = t >> 6;
  for (int jj0 = w * 64; jj0 < padded; jj0 += 256) {
    int jj = jj0 + lane;
    int pred = 0;
    if (jj < n_b) pred = adj_lds[perm[boff + jj]] > 0;
    unsigned long long mword = __ballot(pred);
    if (lane == 0) maskbits[(long)g * 128 + (jj0 >> 6)] = mword;
  }
}

// ---------------------------------------------------------------------------
// S tile = khp_b . khp_b^T (bf16 MFMA, async staging, BK=64 dual-panel).
// SYMMETRY: triangular-linearized grid covers ti <= tj only; epilogue routes
// acc through an LDS tile and writes BOTH orientations with coalesced 16B
// stores, applying the orientation-specific mask via u16 bit-selects.
// ---------------------------------------------------------------------------
__global__ __launch_bounds__(256) void s_gemm(
    const __hip_bfloat16* __restrict__ khp, const int* __restrict__ meta,
    const unsigned long long* __restrict__ maskbits,
    __hip_bfloat16* __restrict__ S) {
  const int b = blockIdx.z;
  const int padded = meta[5 + b];
  const int T = padded >> 7;
  const int pairs = (T * (T + 1)) >> 1;
  int L = blockIdx.x;
  if (L >= pairs) return;
  int ti = 0;
  while (L >= T - ti) { L -= T - ti; ti++; }
  const int tj = ti + L;
  const int boff = meta[b];
  const long soff = meta[9 + b];
  // 34,816 B: As/Bs (2 panels x 8 KB each) during main loop; Ct[128][136].
  __shared__ __align__(16) __hip_bfloat16 smem[128 * 136];
  __hip_bfloat16* As = smem;                  // [2][128*32]
  __hip_bfloat16* Bs = smem + 2 * 128 * 32;   // [2][128*32]
  const int t = threadIdx.x;
  const int lane = t & 63, w = t >> 6;
  const int wm = (w >> 1) * 64, wn = (w & 1) * 64;
  const int quad = lane >> 4, ln = lane & 15;
  const int qr = quad * 8;
  floatx4 acc[4][4];
#pragma unroll
  for (int mi = 0; mi < 4; mi++)
#pragma unroll
    for (int ni = 0; ni < 4; ni++) acc[mi][ni] = (floatx4)0.f;
  const long a_g0 = boff + ti * 128;
  const long b_g0 = boff + tj * 128;
  for (int k0 = 0; k0 < FEAT; k0 += 64) {
    __syncthreads();
#pragma unroll
    for (int p = 0; p < 2; p++)
#pragma unroll
      for (int s = 0; s < 2; s++) {
        int c = t + s * 256;
        int row = c >> 2, off8 = (c & 3) * 8;
        int lo = p * 4096 + row * 32 + off8;  // wave-uniform + lane*16
        async_copy16(&khp[(a_g0 + row) * FEAT + k0 + p * 32 + off8], &As[lo]);
        async_copy16(&khp[(b_g0 + row) * FEAT + k0 + p * 32 + off8], &Bs[lo]);
      }
    __syncthreads();
#pragma unroll
    for (int p = 0; p < 2; p++) {
      short8 af[4], bfr[4];
#pragma unroll
      for (int mi = 0; mi < 4; mi++)
        af[mi] =
            *(const short8*)&As[p * 4096 + (wm + mi * 16 + ln) * 32 + qr];
#pragma unroll
      for (int ni = 0; ni < 4; ni++)
        bfr[ni] =
            *(const short8*)&Bs[p * 4096 + (wn + ni * 16 + ln) * 32 + qr];
#pragma unroll
      for (int mi = 0; mi < 4; mi++)
#pragma unroll
        for (int ni = 0; ni < 4; ni++)
          acc[mi][ni] = __builtin_amdgcn_mfma_f32_16x16x32_bf16(
              af[mi], bfr[ni], acc[mi][ni], 0, 0, 0);
    }
  }
  // ---- epilogue: acc -> LDS tile (scaled bf16, unmasked) ----
  const float scale = 0.04419417382415922f;  // 1/sqrt(512)
  __syncthreads();  // As/Bs dead; reuse as Ct
  __hip_bfloat16* Ct = smem;  // [128][136]
#pragma unroll
  for (int mi = 0; mi < 4; mi++)
#pragma unroll
    for (int ni = 0; ni < 4; ni++) {
      int col = wn + ni * 16 + ln;
#pragma unroll
      for (int reg = 0; reg < 4; reg++) {
        int row = wm + mi * 16 + quad * 4 + reg;
        Ct[row * 136 + col] = __float2bfloat16(acc[mi][ni][reg] * scale);
      }
    }
  __syncthreads();
  const unsigned short negb = f2bf_bits(NEGV);
  // normal orientation: coalesced 16B stores of rows of the ti-block
#pragma unroll
  for (int i = 0; i < 8; i++) {
    int idx = t + i * 256;
    int rl = idx >> 4, c8 = (idx & 15) * 8;
    int rg = ti * 128 + rl;
    int cg = tj * 128 + c8;
    union { short8 v; unsigned short u[8]; } pk;
    pk.v = *(const short8*)&Ct[rl * 136 + c8];
    unsigned long long wbits = maskbits[(long)(boff + rg) * 128 + (cg >> 6)];
#pragma unroll
    for (int e = 0; e < 8; e++)
      if (!((wbits >> ((cg & 63) + e)) & 1ULL)) pk.u[e] = negb;
    *(short8*)&S[soff + (long)rg * padded + cg] = pk.v;
  }
  // mirrored orientation (tj-block rows), skipped on diagonal
  if (ti != tj) {
#pragma unroll
    for (int i = 0; i < 8; i++) {
      int idx = t + i * 256;
      int cl = idx >> 4, r8 = (idx & 15) * 8;
      int rg = tj * 128 + cl;   // output row (column of the computed tile)
      int cg = ti * 128 + r8;   // output col base
      union { short8 v; unsigned short u[8]; } pk;
#pragma unroll
      for (int e = 0; e < 8; e++) {
        __hip_bfloat16 hv = Ct[(r8 + e) * 136 + cl];
        __builtin_memcpy(&pk.u[e], &hv, 2);
      }
      unsigned long long wbits = maskbits[(long)(boff + rg) * 128 + (cg >> 6)];
#pragma unroll
      for (int e = 0; e < 8; e++)
        if (!((wbits >> ((cg & 63) + e)) & 1ULL)) pk.u[e] = negb;
      *(short8*)&S[soff + (long)rg * padded + cg] = pk.v;
    }
  }
}

// ---------------------------------------------------------------------------
// Row softmax in place — ONE WAVE PER ROW (4 rows/block), no LDS, shuffle
// reductions, 3 passes over the L2-resident row. Empty rows flagged.
// ---------------------------------------------------------------------------
__global__ __launch_bounds__(256) void softmax_kernel(
    __hip_bfloat16* __restrict__ S, const int* __restrict__ meta,
    int* __restrict__ flags) {
  const int g = blockIdx.x * 4 + (threadIdx.x >> 6);
  const int lane = threadIdx.x & 63;
  const int b = (g >= meta[1]) + (g >= meta[2]) + (g >= meta[3]);
  const int boff = meta[b];
  const int padded = meta[5 + b];
  const long soff = meta[9 + b];
  __hip_bfloat16* row = S + soff + (long)(g - boff) * padded;
  // pass 1: row max
  float m = -INFINITY;
  for (int j0 = lane * 8; j0 < padded; j0 += 512) {
    union { short8 v; unsigned short u[8]; } pk;
    pk.v = *(const short8*)&row[j0];
#pragma unroll
    for (int e = 0; e < 8; e++) m = fmaxf(m, bf_bits2f(pk.u[e]));
  }
#pragma unroll
  for (int off = 32; off > 0; off >>= 1) m = fmaxf(m, __shfl_xor(m, off));
  if (m < -8e15f) {  // empty (or degenerate) row
    if (lane == 0) flags[g] = 1;
    union { short8 v; unsigned short u[8]; } zz;
#pragma unroll
    for (int e = 0; e < 8; e++) zz.u[e] = 0;
    for (int j0 = lane * 8; j0 < padded; j0 += 512) *(short8*)&row[j0] = zz.v;
    return;
  }
  if (lane == 0) flags[g] = 0;
  // pass 2: sum of exp
  float sum = 0.f;
  for (int j0 = lane * 8; j0 < padded; j0 += 512) {
    union { short8 v; unsigned short u[8]; } pk;
    pk.v = *(const short8*)&row[j0];
#pragma unroll
    for (int e = 0; e < 8; e++) sum += expf(bf_bits2f(pk.u[e]) - m);
  }
#pragma unroll
  for (int off = 32; off > 0; off >>= 1) sum += __shfl_xor(sum, off);
  const float inv = 1.f / sum;
  // pass 3: normalize + store
  for (int j0 = lane * 8; j0 < padded; j0 += 512) {
    union { short8 v; unsigned short u[8]; } pk;
    pk.v = *(const short8*)&row[j0];
#pragma unroll
    for (int e = 0; e < 8; e++)
      pk.u[e] = f2bf_bits(expf(bf_bits2f(pk.u[e]) - m) * inv);
    *(short8*)&row[j0] = pk.v;
  }
}

// ---------------------------------------------------------------------------
// O tile = P_b . vhp_b, 128 rows x 64 features, async staging, BK=64
// dual-panel. Epilogue: ELU + empty-row fallback + scatter to out[perm[g]].
// ---------------------------------------------------------------------------
__global__ __launch_bounds__(256) void pv_gemm(
    const __hip_bfloat16* __restrict__ S, const __hip_bfloat16* __restrict__ vhpT,
    const int* __restrict__ meta, const int* __restrict__ perm,
    const int* __restrict__ flags, const float* __restrict__ cmean,
    float* __restrict__ out) {
  const int b = blockIdx.z;
  const int padded = meta[5 + b];
  const int ti = blockIdx.x;
  if (ti * 128 >= padded) return;
  const int boff = meta[b];
  const int n_b = meta[b + 1] - boff;
  const long soff = meta[9 + b];
  const int poff = meta[14 + b];
  const int f0 = blockIdx.y * 64;
  __shared__ __align__(16) __hip_bfloat16 As[2 * 128 * 32];
  __shared__ __align__(16) __hip_bfloat16 Bs[2 * 64 * 32];
  const int t = threadIdx.x;
  const int lane = t & 63, w = t >> 6;
  const int wm = w * 32;
  const int quad = lane >> 4, ln = lane & 15;
  const int qr = quad * 8;
  floatx4 acc[2][4];
#pragma unroll
  for (int mi = 0; mi < 2; mi++)
#pragma unroll
    for (int ni = 0; ni < 4; ni++) acc[mi][ni] = (floatx4)0.f;
  const long r0 = (long)ti * 128;
  for (int k0 = 0; k0 < padded; k0 += 64) {
    __syncthreads();
#pragma unroll
    for (int p = 0; p < 2; p++) {
#pragma unroll
      for (int s = 0; s < 2; s++) {
        int c = t + s * 256;
        int row = c >> 2, off8 = (c & 3) * 8;
        async_copy16(&S[soff + (r0 + row) * padded + k0 + p * 32 + off8],
                     &As[p * 4096 + row * 32 + off8]);
      }
      {
        int row = t >> 2, off8 = (t & 3) * 8;
        async_copy16(
            &vhpT[(long)(f0 + row) * VHPT_W + poff + k0 + p * 32 + off8],
            &Bs[p * 2048 + row * 32 + off8]);
      }
    }
    __syncthreads();
#pragma unroll
    for (int p = 0; p < 2; p++) {
      short8 af[2], bfr[4];
#pragma unroll
      for (int mi = 0; mi < 2; mi++)
        af[mi] =
            *(const short8*)&As[p * 4096 + (wm + mi * 16 + ln) * 32 + qr];
#pragma unroll
      for (int ni = 0; ni < 4; ni++)
        bfr[ni] = *(const short8*)&Bs[p * 2048 + (ni * 16 + ln) * 32 + qr];
#pragma unroll
      for (int mi = 0; mi < 2; mi++)
#pragma unroll
        for (int ni = 0; ni < 4; ni++)
          acc[mi][ni] = __builtin_amdgcn_mfma_f32_16x16x32_bf16(
              af[mi], bfr[ni], acc[mi][ni], 0, 0, 0);
    }
  }
#pragma unroll
  for (int mi = 0; mi < 2; mi++) {
#pragma unroll
    for (int reg = 0; reg < 4; reg++) {
      int r = ti * 128 + wm + mi * 16 + quad * 4 + reg;
      if (r < n_b) {
        int g = boff + r;
        int node = perm[g];
        int fl = flags[g];
#pragma unroll
        for (int ni = 0; ni < 4; ni++) {
          int fc = f0 + ni * 16 + ln;
          float v = fl ? cmean[fc] * (1.f / (float)N_NODES)
                       : acc[mi][ni][reg];
          v = v > 0.f ? v : expm1f(v);
          out[(long)node * FEAT + fc] = v;
        }
      }
    }
  }
}

// ===========================================================================
// Slow-path fallback (only if ws_size < WS_NEEDED): round-1 implementation.
// ===========================================================================
__global__ __launch_bounds__(256) void gemm_dual(
    const float* __restrict__ A, const float* __restrict__ Wk,
    const float* __restrict__ Wv, float* __restrict__ kh,
    float* __restrict__ vh) {
  __shared__ float As[32][33];
  __shared__ float Bk[32][33];
  __shared__ float Bv[32][33];
  const int tid = threadIdx.x;
  const int row0 = blockIdx.x * 32;
  const int col0 = blockIdx.y * 32;
  const int tx = tid & 15, ty = tid >> 4;
  float ck00 = 0.f, ck01 = 0.f, ck10 = 0.f, ck11 = 0.f;
  float cv00 = 0.f, cv01 = 0.f, cv10 = 0.f, cv11 = 0.f;
  for (int kt = 0; kt < FEAT; kt += 32) {
#pragma unroll
    for (int t = 0; t < 4; t++) {
      int e = tid + t * 256;
      int r = e >> 5, c = e & 31;
      As[r][c] = A[(long)(row0 + r) * FEAT + kt + c];
      Bk[r][c] = Wk[(long)(kt + r) * FEAT + col0 + c];
      Bv[r][c] = Wv[(long)(kt + r) * FEAT + col0 + c];
    }
    __syncthreads();
#pragma unroll
    for (int kk = 0; kk < 32; kk++) {
      float a0 = As[ty * 2][kk], a1 = As[ty * 2 + 1][kk];
      float bk0 = Bk[kk][tx * 2], bk1 = Bk[kk][tx * 2 + 1];
      float bv0 = Bv[kk][tx * 2], bv1 = Bv[kk][tx * 2 + 1];
      ck00 += a0 * bk0; ck01 += a0 * bk1;
      ck10 += a1 * bk0; ck11 += a1 * bk1;
      cv00 += a0 * bv0; cv01 += a0 * bv1;
      cv10 += a1 * bv0; cv11 += a1 * bv1;
    }
    __syncthreads();
  }
  const int r0 = row0 + ty * 2, c0 = col0 + tx * 2;
  kh[(long)r0 * FEAT + c0] = ck00;       kh[(long)r0 * FEAT + c0 + 1] = ck01;
  kh[(long)(r0 + 1) * FEAT + c0] = ck10; kh[(long)(r0 + 1) * FEAT + c0 + 1] = ck11;
  vh[(long)r0 * FEAT + c0] = cv00;       vh[(long)r0 * FEAT + c0 + 1] = cv01;
  vh[(long)(r0 + 1) * FEAT + c0] = cv10; vh[(long)(r0 + 1) * FEAT + c0 + 1] = cv11;
}

__global__ __launch_bounds__(64) void bucket_kernel(
    const float* __restrict__ kh, const float* __restrict__ rot,
    int* __restrict__ buckets) {
  const int i = blockIdx.x;
  const int lane = threadIdx.x;
  double r0 = 0.0, r1 = 0.0;
  for (int h = lane; h < FEAT; h += 64) {
    double a = (double)kh[(long)i * FEAT + h];
    r0 += a * (double)rot[2 * h];
    r1 += a * (double)rot[2 * h + 1];
  }
#pragma unroll
  for (int off = 32; off > 0; off >>= 1) {
    r0 += __shfl_down(r0, off);
    r1 += __shfl_down(r1, off);
  }
  if (lane == 0) {
    int b = 0;
    double best = r0;
    if (r1 > best)  { best = r1;  b = 1; }
    if (-r0 > best) { best = -r0; b = 2; }
    if (-r1 > best) { best = -r1; b = 3; }
    buckets[i] = b;
  }
}

__global__ __launch_bounds__(256) void attn_kernel(
    const float* __restrict__ kh, const float* __restrict__ vh,
    const int* __restrict__ adj, const int* __restrict__ buckets,
    float* __restrict__ out) {
  __shared__ float khi[FEAT];
  __shared__ float pbuf[N_NODES];
  __shared__ unsigned short jlist[N_NODES];
  __shared__ int cnt_sh;
  __shared__ float red[256];
  const int i = blockIdx.x;
  const int tid = threadIdx.x;
  if (tid == 0) cnt_sh = 0;
  for (int k = tid; k < FEAT; k += 256) khi[k] = kh[(long)i * FEAT + k];
  const int mybucket = buckets[i];
  __syncthreads();
  const int* adjrow = adj + (long)i * N_NODES;
  for (int j = tid; j < N_NODES; j += 256) {
    if (adjrow[j] > 0 && buckets[j] == mybucket) {
      int idx = atomicAdd(&cnt_sh, 1);
      jlist[idx] = (unsigned short)j;
    }
  }
  __syncthreads();
  const int cnt = cnt_sh;
  float mloc = -INFINITY;
  for (int idx = tid; idx < cnt; idx += 256) {
    int j = jlist[idx];
    const float4* kj = (const float4*)(kh + (long)j * FEAT);
    const float4* ki = (const float4*)khi;
    float acc = 0.f;
#pragma unroll 8
    for (int k = 0; k < FEAT / 4; k++) {
      float4 a = ki[k];
      float4 b = kj[k];
      acc += a.x * b.x + a.y * b.y + a.z * b.z + a.w * b.w;
    }
    float s = acc * 0.04419417382415922f;
    pbuf[idx] = s;
    mloc = fmaxf(mloc, s);
  }
  red[tid] = mloc;
  __syncthreads();
#pragma unroll
  for (int off = 128; off > 0; off >>= 1) {
    if (tid < off) red[tid] = fmaxf(red[tid], red[tid + off]);
    __syncthreads();
  }
  const float m = red[0];
  __syncthreads();
  float lloc = 0.f;
  for (int idx = tid; idx < cnt; idx += 256) {
    float p = expf(pbuf[idx] - m);
    pbuf[idx] = p;
    lloc += p;
  }
  red[tid] = lloc;
  __syncthreads();
#pragma unroll
  for (int off = 128; off > 0; off >>= 1) {
    if (tid < off) red[tid] += red[tid + off];
    __syncthreads();
  }
  const float l = red[0];
  __syncthreads();
  const int f = 2 * tid;
  float acc0 = 0.f, acc1 = 0.f;
  if (cnt > 0) {
#pragma unroll 4
    for (int idx = 0; idx < cnt; idx++) {
      int j = jlist[idx];
      float p = pbuf[idx];
      float2 v = *(const float2*)(vh + (long)j * FEAT + f);
      acc0 += p * v.x;
      acc1 += p * v.y;
    }
    float invl = 1.f / l;
    acc0 *= invl;
    acc1 *= invl;
  } else {
    for (int j = 0; j < N_NODES; j++) {
      float2 v = *(const float2*)(vh + (long)j * FEAT + f);
      acc0 += v.x;
      acc1 += v.y;
    }
    acc0 *= (1.f / (float)N_NODES);
    acc1 *= (1.f / (float)N_NODES);
  }
  acc0 = acc0 > 0.f ? acc0 : expm1f(acc0);
  acc1 = acc1 > 0.f ? acc1 : expm1f(acc1);
  *(float2*)(out + (long)i * FEAT + f) = make_float2(acc0, acc1);
}

extern "C" void kernel_launch(void* const* d_in, const int* in_sizes, int n_in,
                              void* d_out, int out_size, void* d_ws,
                              size_t ws_size, hipStream_t stream) {
  const float* input = (const float*)d_in[0];
  const int* adj = (const int*)d_in[1];
  const float* rot = (const float*)d_in[2];
  const float* kW = (const float*)d_in[3];
  const float* vW = (const float*)d_in[4];
  float* out = (float*)d_out;

  char* ws = (char*)d_ws;

  if (ws_size >= WS_NEEDED) {
    float* kh = (float*)(ws + OFF_KH);
    float* vh = (float*)(ws + OFF_VH);
    __hip_bfloat16* khp = (__hip_bfloat16*)(ws + OFF_KHP);
    __hip_bfloat16* vhpT = (__hip_bfloat16*)(ws + OFF_VHPT);
    unsigned long long* maskbits = (unsigned long long*)(ws + OFF_MASK);
    __hip_bfloat16* S = (__hip_bfloat16*)(ws + OFF_S);
    int* perm = (int*)(ws + OFF_PERM);
    int* flags = (int*)(ws + OFF_FLAGS);
    int* buckets = (int*)(ws + OFF_BUCK);
    int* meta = (int*)(ws + OFF_META);
    float* cmean = (float*)(ws + OFF_CMEAN);
    __hip_bfloat16* Ahi = (__hip_bfloat16*)(ws + OFF_AHI);
    __hip_bfloat16* Alo = (__hip_bfloat16*)(ws + OFF_ALO);
    __hip_bfloat16* WkhiT = (__hip_bfloat16*)(ws + OFF_WKHI);
    __hip_bfloat16* WkloT = (__hip_bfloat16*)(ws + OFF_WKLO);
    __hip_bfloat16* WvhiT = (__hip_bfloat16*)(ws + OFF_WVHI);
    __hip_bfloat16* WvloT = (__hip_bfloat16*)(ws + OFF_WVLO);
    double* cw = (double*)(ws + OFF_CW);

    convert_input<<<4096, 256, 0, stream>>>(input, Ahi, Alo);
    convert_w<<<dim3(8, 8, 2), 256, 0, stream>>>(kW, vW, WkhiT, WkloT, WvhiT,
                                                 WvloT);
    mfma_dual<<<dim3(64, 4, 2), 256, 0, stream>>>(Ahi, Alo, WkhiT, WkloT,
                                                  WvhiT, WvloT, kh, vh);
    cw_kernel<<<512, 64, 0, stream>>>(kW, rot, cw);
    rv_bucket_kernel<<<N_NODES, 64, 0, stream>>>(input, cw, buckets);
    sort_kernel<<<1, 256, 0, stream>>>(buckets, perm, meta, cmean);
    gather_khp_kernel<<<N_NODES + 128, 256, 0, stream>>>(kh, perm, khp);
    transpose_vhpT_kernel<<<dim3(VHPT_W / 64, FEAT / 64), 256, 0, stream>>>(
        vh, perm, meta, vhpT, cmean);
    maskpack_kernel<<<N_NODES, 256, 0, stream>>>(adj, perm, meta, maskbits);
    s_gemm<<<dim3(2080, 1, 4), 256, 0, stream>>>(khp, meta, maskbits, S);
    softmax_kernel<<<N_NODES / 4, 256, 0, stream>>>(S, meta, flags);
    pv_gemm<<<dim3(64, 8, 4), 256, 0, stream>>>(S, vhpT, meta, perm, flags,
                                                cmean, out);
  } else {
    float* kh = (float*)(ws + 0UL);
    float* vh = (float*)(ws + 16777216UL);
    int* buckets = (int*)(ws + 33554432UL);
    dim3 gemm_grid(N_NODES / 32, FEAT / 32);
    gemm_dual<<<gemm_grid, 256, 0, stream>>>(input, kW, vW, kh, vh);
    bucket_kernel<<<N_NODES, 64, 0, stream>>>(kh, rot, buckets);
    attn_kernel<<<N_NODES, 256, 0, stream>>>(kh, vh, adj, buckets, out);
  }
}